// Round 4
// 818.748 us; speedup vs baseline: 1.1934x; 1.1934x over previous
//
#include <hip/hip_runtime.h>
#include <math.h>

#define FEAT 512
#define HID  16
#define NCLS 40

// ---------------- CSR build ----------------

__global__ void count_kernel(const int* __restrict__ dst, int* __restrict__ cnt, int E) {
    int e = blockIdx.x * blockDim.x + threadIdx.x;
    if (e < E) atomicAdd(&cnt[dst[e]], 1);
}

// ---- hierarchical scan: 1024 elements per block, coalesced int4 loads ----
// scan1: per-block exclusive scan of cnt -> off (block-local), block totals -> bsum.
// Also computes dinv[i] = rsqrt(deg_i + 1) directly from cnt (folds dinv_kernel).
__global__ __launch_bounds__(256) void scan1_kernel(const int* __restrict__ cnt,
                                                    int* __restrict__ off,
                                                    int* __restrict__ bsum,
                                                    float* __restrict__ dinv, int N) {
    __shared__ int s[256];
    int t = threadIdx.x;
    int idx = blockIdx.x * 1024 + t * 4;

    int4 v = {0, 0, 0, 0};
    if (idx + 3 < N) {
        v = *(const int4*)(cnt + idx);
    } else {
        if (idx + 0 < N) v.x = cnt[idx + 0];
        if (idx + 1 < N) v.y = cnt[idx + 1];
        if (idx + 2 < N) v.z = cnt[idx + 2];
        if (idx + 3 < N) v.w = cnt[idx + 3];
    }
    int tsum = v.x + v.y + v.z + v.w;

    s[t] = tsum;
    __syncthreads();
    // Hillis-Steele inclusive scan over 256 thread partials
    for (int o = 1; o < 256; o <<= 1) {
        int add = (t >= o) ? s[t - o] : 0;
        __syncthreads();
        s[t] += add;
        __syncthreads();
    }
    int excl = (t > 0) ? s[t - 1] : 0;

    // write block-local exclusive scan (coalesced int4 where possible)
    int4 o4;
    o4.x = excl;
    o4.y = o4.x + v.x;
    o4.z = o4.y + v.y;
    o4.w = o4.z + v.z;
    if (idx + 3 < N) {
        *(int4*)(off + idx) = o4;
    } else {
        if (idx + 0 < N) off[idx + 0] = o4.x;
        if (idx + 1 < N) off[idx + 1] = o4.y;
        if (idx + 2 < N) off[idx + 2] = o4.z;
        if (idx + 3 < N) off[idx + 3] = o4.w;
    }

    // dinv from degree (cnt) + self-loop
    float4 d4;
    d4.x = rsqrtf((float)v.x + 1.0f);
    d4.y = rsqrtf((float)v.y + 1.0f);
    d4.z = rsqrtf((float)v.z + 1.0f);
    d4.w = rsqrtf((float)v.w + 1.0f);
    if (idx + 3 < N) {
        *(float4*)(dinv + idx) = d4;
    } else {
        if (idx + 0 < N) dinv[idx + 0] = d4.x;
        if (idx + 1 < N) dinv[idx + 1] = d4.y;
        if (idx + 2 < N) dinv[idx + 2] = d4.z;
        if (idx + 3 < N) dinv[idx + 3] = d4.w;
    }

    if (t == 255) bsum[blockIdx.x] = s[255];
}

// scan2: single small block scans nb (<=128) block sums in place (exclusive),
// writes grand total to off[N].
__global__ void scan2_kernel(int* __restrict__ bsum, int* __restrict__ off, int nb, int N) {
    __shared__ int s[128];
    int t = threadIdx.x;
    int v = (t < nb) ? bsum[t] : 0;
    s[t] = v;
    __syncthreads();
    for (int o = 1; o < 128; o <<= 1) {
        int add = (t >= o) ? s[t - o] : 0;
        __syncthreads();
        s[t] += add;
        __syncthreads();
    }
    if (t < nb) bsum[t] = s[t] - v;   // exclusive
    if (t == 127) off[N] = s[127];
}

// scan3: add scanned block offsets into off.
__global__ __launch_bounds__(256) void scan3_kernel(int* __restrict__ off,
                                                    const int* __restrict__ bsum, int N) {
    int add = bsum[blockIdx.x];
    int idx = blockIdx.x * 1024 + threadIdx.x * 4;
    if (idx + 3 < N) {
        int4 v = *(int4*)(off + idx);
        v.x += add; v.y += add; v.z += add; v.w += add;
        *(int4*)(off + idx) = v;
    } else {
        if (idx + 0 < N) off[idx + 0] += add;
        if (idx + 1 < N) off[idx + 1] += add;
        if (idx + 2 < N) off[idx + 2] += add;
        if (idx + 3 < N) off[idx + 3] += add;
    }
}

__global__ void fill_kernel(const int* __restrict__ src, const int* __restrict__ dst,
                            const int* __restrict__ off, int* __restrict__ fill,
                            int* __restrict__ csr, int E) {
    int e = blockIdx.x * blockDim.x + threadIdx.x;
    if (e < E) {
        int d = dst[e];
        int p = atomicAdd(&fill[d], 1);
        csr[off[d] + p] = src[e];
    }
}

// ---------------- GEMM1: h1 = x @ W1  [N x 16] ----------------
// block = 256 threads, 16 rows per block. x tile + W1^T staged in LDS,
// both padded to stride 516 floats (=129 float4) for bank-conflict freedom:
// bank(516*r + k) = (4r + k) % 32 -> rows land in distinct bank groups.
__global__ __launch_bounds__(256) void gemm1_kernel(const float* __restrict__ x,
                                                    const float* __restrict__ W1,
                                                    float* __restrict__ h1, int N) {
    __shared__ float4 xt4[16 * 129];
    __shared__ float4 wt4[16 * 129];
    int t = threadIdx.x;

    // stage W1 transposed: W1[k][o] -> wt[o*516 + k]
    float* wt = (float*)wt4;
#pragma unroll
    for (int i = 0; i < 32; ++i) {
        int f = t + i * 256;           // 8192 elements
        int k = f >> 4, o = f & 15;
        wt[o * 516 + k] = W1[f];
    }

    int base = blockIdx.x * 16;        // N divisible by 16 (100000/16 = 6250)
    {
        const float4* xg = (const float4*)(x + (size_t)base * FEAT);
#pragma unroll
        for (int i = 0; i < 8; ++i) {
            int f = t + i * 256;       // 2048 float4
            int r = f >> 7, k4 = f & 127;
            xt4[r * 129 + k4] = xg[r * 128 + k4];
        }
    }
    __syncthreads();

    int r = t >> 4, o = t & 15;
    const float4* xr = (const float4*)((const float*)xt4 + r * 516);
    const float4* wr = (const float4*)((const float*)wt4 + o * 516);
    float acc = 0.f;
#pragma unroll 8
    for (int k = 0; k < 128; ++k) {
        float4 a = xr[k];
        float4 b = wr[k];
        acc += a.x * b.x + a.y * b.y + a.z * b.z + a.w * b.w;
    }
    h1[(size_t)(base + r) * HID + o] = acc;
}

// ---------------- Aggregation: out[i] = di*(sum_s dinv[s]*h[s] + di*h[i]) (+bias, relu)
// wave per node; lane = nb*16 + f : 4 neighbors x 16 features per iteration.
template <bool RELU>
__global__ __launch_bounds__(256) void agg_kernel(const float* __restrict__ h,
                                                  const float* __restrict__ dinv,
                                                  const int* __restrict__ off,
                                                  const int* __restrict__ csr,
                                                  const float* __restrict__ bias,
                                                  float* __restrict__ out, int N) {
    int wave = (blockIdx.x * 256 + threadIdx.x) >> 6;
    int lane = threadIdx.x & 63;
    if (wave >= N) return;
    int i = wave;
    int nb = lane >> 4, f = lane & 15;
    int o0 = off[i];
    int ne = off[i + 1] - o0;
    float acc = 0.f;
    for (int b = 0; b < ne; b += 4) {
        int j = b + nb;
        if (j < ne) {
            int s = csr[o0 + j];
            acc += dinv[s] * h[s * HID + f];
        }
    }
    acc += __shfl_xor(acc, 16);
    acc += __shfl_xor(acc, 32);
    float di = dinv[i];
    float v = di * (acc + di * h[i * HID + f]);
    if (bias) v += bias[f];
    if (RELU) v = fmaxf(v, 0.f);
    if (lane < 16) out[i * HID + f] = v;
}

// ---------------- Final: v = g @ W2 + b2, then log_softmax ----------------
__global__ __launch_bounds__(256) void final_kernel(const float* __restrict__ g,
                                                    const float* __restrict__ W2,
                                                    const float* __restrict__ b2,
                                                    float* __restrict__ out, int N) {
    __shared__ float w2s[HID * NCLS];
    __shared__ float b2s[NCLS];
    int t = threadIdx.x;
    for (int f = t; f < HID * NCLS; f += 256) w2s[f] = W2[f];
    if (t < NCLS) b2s[t] = b2[t];
    __syncthreads();

    int wave = (blockIdx.x * 256 + t) >> 6;
    int lane = t & 63;
    if (wave >= N) return;
    int i = wave;

    float acc = 0.f;
    float v = -1e30f;
    if (lane < NCLS) {
        acc = b2s[lane];
        const float* gr = g + (size_t)i * HID;
#pragma unroll
        for (int k = 0; k < HID; ++k) acc += gr[k] * w2s[k * NCLS + lane];
        v = acc;
    }
    // wave max over active lanes (inactive carry -1e30)
    for (int d = 32; d >= 1; d >>= 1) v = fmaxf(v, __shfl_xor(v, d));
    float e = (lane < NCLS) ? __expf(acc - v) : 0.f;
    float s = e;
    for (int d = 32; d >= 1; d >>= 1) s += __shfl_xor(s, d);
    if (lane < NCLS) out[(size_t)i * NCLS + lane] = acc - v - __logf(s);
}

// ---------------- launch ----------------

extern "C" void kernel_launch(void* const* d_in, const int* in_sizes, int n_in,
                              void* d_out, int out_size, void* d_ws, size_t ws_size,
                              hipStream_t stream) {
    const float* x  = (const float*)d_in[0];
    const int*   ei = (const int*)d_in[1];
    const float* W1 = (const float*)d_in[2];
    const float* b1 = (const float*)d_in[3];
    const float* W2 = (const float*)d_in[4];
    const float* b2 = (const float*)d_in[5];

    int N = in_sizes[0] / FEAT;   // 100000
    int E = in_sizes[1] / 2;      // 3200000
    const int* src = ei;
    const int* dst = ei + E;

    char* ws = (char*)d_ws;
    size_t p = 0;
    auto alloc = [&](size_t bytes) -> void* {
        void* r = ws + p;
        p = (p + bytes + 15) & ~(size_t)15;
        return r;
    };
    int*   off  = (int*)alloc((size_t)(N + 1) * 4);
    int*   cnt  = (int*)alloc((size_t)N * 4);        // also reused as fill counters
    float* dinv = (float*)alloc((size_t)N * 4);
    int*   csr  = (int*)alloc((size_t)E * 4);
    float* h1   = (float*)alloc((size_t)N * HID * 4);
    float* a1   = (float*)alloc((size_t)N * HID * 4);
    float* g    = (float*)alloc((size_t)N * HID * 4);
    int*   bsum = (int*)alloc((size_t)128 * 4);

    int nb = (N + 1023) / 1024;   // 98 blocks for N=100000

    hipMemsetAsync(cnt, 0, (size_t)N * 4, stream);
    count_kernel<<<(E + 255) / 256, 256, 0, stream>>>(dst, cnt, E);
    scan1_kernel<<<nb, 256, 0, stream>>>(cnt, off, bsum, dinv, N);
    scan2_kernel<<<1, 128, 0, stream>>>(bsum, off, nb, N);
    scan3_kernel<<<nb, 256, 0, stream>>>(off, bsum, N);
    hipMemsetAsync(cnt, 0, (size_t)N * 4, stream);
    fill_kernel<<<(E + 255) / 256, 256, 0, stream>>>(src, dst, off, cnt, csr, E);

    gemm1_kernel<<<N / 16, 256, 0, stream>>>(x, W1, h1, N);
    agg_kernel<true><<<(N + 3) / 4, 256, 0, stream>>>(h1, dinv, off, csr, b1, a1, N);
    agg_kernel<false><<<(N + 3) / 4, 256, 0, stream>>>(a1, dinv, off, csr, nullptr, g, N);
    final_kernel<<<(N + 3) / 4, 256, 0, stream>>>(g, W2, b2, (float*)d_out, N);
}